// Round 1
// baseline (110.549 us; speedup 1.0000x reference)
//
#include <hip/hip_runtime.h>
#include <math.h>

namespace {
constexpr int L1 = 13;   // 12 history layers + current
constexpr int B  = 4;
constexpr int S  = 1024;
constexpr int D  = 1024;
constexpr int NCH = 32;        // s-chunks for the scan
constexpr int CH  = S / NCH;   // 32

// float offsets into workspace
constexpr int OFF_SCAL   = 0;                     // [0]=sum(w*gamma), [1]=sum(w*beta)
constexpr int OFF_M      = 8;                     // B floats (per-batch score max)
constexpr int OFF_SCORES = 16;                    // [B][L1][S]
constexpr int OFF_Z      = OFF_SCORES + L1*B*S;   // [B][S]
constexpr int OFF_ZCUM   = OFF_Z + B*S;           // [B][S]
constexpr int OFF_CS     = OFF_ZCUM + B*S;        // [B][NCH][D] chunk partial sums
constexpr float EPS = 1e-5f;
}

// K0: scalars sum(w*gamma), sum(w*beta)
__global__ void arm_k0_wdot(const float* __restrict__ w, const float* __restrict__ gamma,
                            const float* __restrict__ beta, float* __restrict__ ws) {
    int tid = threadIdx.x;  // 256
    float sg = 0.f, sb = 0.f;
    for (int d = tid; d < D; d += 256) {
        float wv = w[d];
        sg += wv * gamma[d];
        sb += wv * beta[d];
    }
    __shared__ float lg[256], lb[256];
    lg[tid] = sg; lb[tid] = sb; __syncthreads();
    for (int off = 128; off > 0; off >>= 1) {
        if (tid < off) { lg[tid] += lg[tid + off]; lb[tid] += lb[tid + off]; }
        __syncthreads();
    }
    if (tid == 0) { ws[OFF_SCAL] = lg[0]; ws[OFF_SCAL + 1] = lb[0]; }
}

// K1: per-row fused LayerNorm-dot scores. One wave (64 lanes) per row of V.
// scores[b,l,s] = rstd*(sum(w*g*V) - mu*sum(w*g)) + sum(w*beta)
__global__ void arm_k1_scores(const float* __restrict__ hist, const float* __restrict__ cur,
                              const float* __restrict__ w, const float* __restrict__ gamma,
                              float* __restrict__ ws) {
    int wave = (blockIdx.x * blockDim.x + threadIdx.x) >> 6;  // row id in [0, L1*B*S)
    int lane = threadIdx.x & 63;
    const float* row = (wave < 12 * B * S) ? hist + (size_t)wave * D
                                           : cur + (size_t)(wave - 12 * B * S) * D;
    float s1 = 0.f, s2 = 0.f, sw = 0.f;
#pragma unroll
    for (int j = 0; j < 4; j++) {
        int d = (j * 64 + lane) * 4;
        float4 v  = *(const float4*)(row + d);
        float4 wv = *(const float4*)(w + d);
        float4 gv = *(const float4*)(gamma + d);
        s1 += v.x + v.y + v.z + v.w;
        s2 += v.x * v.x + v.y * v.y + v.z * v.z + v.w * v.w;
        sw += wv.x * gv.x * v.x + wv.y * gv.y * v.y + wv.z * gv.z * v.z + wv.w * gv.w * v.w;
    }
#pragma unroll
    for (int off = 32; off > 0; off >>= 1) {
        s1 += __shfl_down(s1, off);
        s2 += __shfl_down(s2, off);
        sw += __shfl_down(sw, off);
    }
    if (lane == 0) {
        float swg = ws[OFF_SCAL], swb = ws[OFF_SCAL + 1];
        float mu   = s1 * (1.0f / D);
        float var  = s2 * (1.0f / D) - mu * mu;
        float rstd = rsqrtf(var + EPS);
        float score = rstd * (sw - mu * swg) + swb;
        int l = wave / (B * S);
        int rem = wave % (B * S);
        int b = rem / S, s = rem % S;
        ws[OFF_SCORES + (b * L1 + l) * S + s] = score;
    }
}

// K2: per-batch global max of scores
__global__ void arm_k2_max(float* __restrict__ ws) {
    int b = blockIdx.x, tid = threadIdx.x;  // 256
    const float* sc = ws + OFF_SCORES + b * L1 * S;
    float m = -1e30f;
    for (int i = tid; i < L1 * S; i += 256) m = fmaxf(m, sc[i]);
    __shared__ float lm[256];
    lm[tid] = m; __syncthreads();
    for (int off = 128; off > 0; off >>= 1) {
        if (tid < off) lm[tid] = fmaxf(lm[tid], lm[tid + off]);
        __syncthreads();
    }
    if (tid == 0) ws[OFF_M + b] = lm[0];
}

// K3: z[b,s] = sum_l exp(scores[b,l,s] - M[b])
__global__ void arm_k3_z(float* __restrict__ ws) {
    int i = blockIdx.x * 256 + threadIdx.x;  // [0, B*S)
    int b = i / S, s = i % S;
    float M = ws[OFF_M + b];
    const float* sc = ws + OFF_SCORES + b * L1 * S + s;
    float z = 0.f;
#pragma unroll
    for (int l = 0; l < L1; l++) z += expf(sc[l * S] - M);
    ws[OFF_Z + i] = z;
}

// K4: Zcum[b,s] = inclusive prefix sum of z over s. One block per b.
__global__ void arm_k4_zcum(float* __restrict__ ws) {
    int b = blockIdx.x, tid = threadIdx.x;  // 256 threads, 4 elems each
    const float* z = ws + OFF_Z + b * S;
    float* zc = ws + OFF_ZCUM + b * S;
    float v[4];
    float loc = 0.f;
#pragma unroll
    for (int j = 0; j < 4; j++) { v[j] = z[tid * 4 + j]; loc += v[j]; }
    __shared__ float lds[256];
    lds[tid] = loc; __syncthreads();
    for (int off = 1; off < 256; off <<= 1) {
        float t = (tid >= off) ? lds[tid - off] : 0.f;
        __syncthreads();
        lds[tid] += t;
        __syncthreads();
    }
    float run = lds[tid] - loc;  // exclusive offset
#pragma unroll
    for (int j = 0; j < 4; j++) { run += v[j]; zc[tid * 4 + j] = run; }
}

// K5: U[b,s,:] = sum_l exp(scores[b,l,s]-M[b]) * V[l,b,s,:]   (U lives in d_out)
__global__ void arm_k5_U(const float* __restrict__ hist, const float* __restrict__ cur,
                         const float* __restrict__ ws, float* __restrict__ U) {
    int blk = blockIdx.x;  // b*S + s
    int b = blk / S, s = blk % S;
    int d = threadIdx.x * 4;  // 256 threads x float4 covers D
    __shared__ float pl[L1];
    if (threadIdx.x < L1) {
        float M = ws[OFF_M + b];
        pl[threadIdx.x] = expf(ws[OFF_SCORES + b * L1 * S + threadIdx.x * S + s] - M);
    }
    __syncthreads();
    float4 acc = {0.f, 0.f, 0.f, 0.f};
#pragma unroll
    for (int l = 0; l < L1; l++) {
        const float* vrow = (l < 12) ? hist + (((size_t)l * B + b) * S + s) * D
                                     : cur + ((size_t)b * S + s) * D;
        float4 v = *(const float4*)(vrow + d);
        float p = pl[l];
        acc.x += p * v.x; acc.y += p * v.y; acc.z += p * v.z; acc.w += p * v.w;
    }
    *(float4*)(U + ((size_t)b * S + s) * D + d) = acc;
}

// K6a: per-chunk partial column sums of U
__global__ void arm_k6a_csum(const float* __restrict__ U, float* __restrict__ ws) {
    int blk = blockIdx.x;                 // b*NCH*(D/256) + ch*(D/256) + dblk
    int dblk = blk % (D / 256);
    int rem = blk / (D / 256);
    int ch = rem % NCH, b = rem / NCH;
    int d = dblk * 256 + threadIdx.x;
    const float* Ub = U + ((size_t)b * S + ch * CH) * D + d;
    float sum = 0.f;
#pragma unroll
    for (int j = 0; j < CH; j++) sum += Ub[(size_t)j * D];
    ws[OFF_CS + (b * NCH + ch) * D + d] = sum;
}

// K6b: exclusive scan of chunk sums over ch, in place
__global__ void arm_k6b_cscan(float* __restrict__ ws) {
    int blk = blockIdx.x;  // b*(D/256) + dblk
    int dblk = blk % (D / 256);
    int b = blk / (D / 256);
    int d = dblk * 256 + threadIdx.x;
    float* cs = ws + OFF_CS + b * NCH * D + d;
    float run = 0.f;
#pragma unroll
    for (int ch = 0; ch < NCH; ch++) {
        float v = cs[(size_t)ch * D];
        cs[(size_t)ch * D] = run;
        run += v;
    }
}

// K6c: local cumsum + divide by Zcum, in place over U (= d_out) -> h
__global__ void arm_k6c_final(float* __restrict__ U, const float* __restrict__ ws) {
    int blk = blockIdx.x;  // same mapping as k6a
    int dblk = blk % (D / 256);
    int rem = blk / (D / 256);
    int ch = rem % NCH, b = rem / NCH;
    int d = dblk * 256 + threadIdx.x;
    float run = ws[OFF_CS + (b * NCH + ch) * D + d];
    const float* zc = ws + OFF_ZCUM + b * S + ch * CH;
    float* Ub = U + ((size_t)b * S + ch * CH) * D + d;
#pragma unroll
    for (int j = 0; j < CH; j++) {
        run += Ub[(size_t)j * D];
        Ub[(size_t)j * D] = run / zc[j];
    }
}

extern "C" void kernel_launch(void* const* d_in, const int* in_sizes, int n_in,
                              void* d_out, int out_size, void* d_ws, size_t ws_size,
                              hipStream_t stream) {
    const float* hist  = (const float*)d_in[0];  // [12,B,S,D]
    const float* cur   = (const float*)d_in[1];  // [B,S,D]
    const float* w     = (const float*)d_in[2];  // [D]
    const float* gamma = (const float*)d_in[3];  // [D]
    const float* beta  = (const float*)d_in[4];  // [D]
    float* out = (float*)d_out;                  // [B,S,D]
    float* ws  = (float*)d_ws;

    arm_k0_wdot<<<1, 256, 0, stream>>>(w, gamma, beta, ws);
    arm_k1_scores<<<(L1 * B * S) / 4, 256, 0, stream>>>(hist, cur, w, gamma, ws);
    arm_k2_max<<<B, 256, 0, stream>>>(ws);
    arm_k3_z<<<(B * S) / 256, 256, 0, stream>>>(ws);
    arm_k4_zcum<<<B, 256, 0, stream>>>(ws);
    arm_k5_U<<<B * S, 256, 0, stream>>>(hist, cur, ws, out);
    arm_k6a_csum<<<B * NCH * (D / 256), 256, 0, stream>>>(out, ws);
    arm_k6b_cscan<<<B * (D / 256), 256, 0, stream>>>(ws);
    arm_k6c_final<<<B * NCH * (D / 256), 256, 0, stream>>>(out, ws);
}

// Round 2
// 88.582 us; speedup vs baseline: 1.2480x; 1.2480x over previous
//
#include <hip/hip_runtime.h>
#include <math.h>

namespace {
constexpr int L1 = 13;   // 12 history layers + current
constexpr int B  = 4;
constexpr int S  = 1024;
constexpr int D  = 1024;
constexpr int NCH = 32;        // s-chunks for the scan
constexpr int CH  = S / NCH;   // 32

// float offsets into workspace
constexpr int OFF_SCAL = 0;                    // [0]=sum(w*gamma), [1]=sum(w*beta)
constexpr int OFF_WG   = 8;                    // [D] w*gamma
constexpr int OFF_Z    = OFF_WG + D;           // [B][S]
constexpr int OFF_ZCUM = OFF_Z + B * S;        // [B][S]
constexpr int OFF_CS   = OFF_ZCUM + B * S;     // [B][NCH][D] chunk partial sums
constexpr float EPS = 1e-5f;
}

// K0: wg[d] = w*gamma, scalars sum(w*gamma), sum(w*beta). 256 threads x float4.
__global__ void arm_k0_prep(const float* __restrict__ w, const float* __restrict__ gamma,
                            const float* __restrict__ beta, float* __restrict__ ws) {
    int tid = threadIdx.x;
    int d = tid * 4;
    float4 wv = *(const float4*)(w + d);
    float4 gv = *(const float4*)(gamma + d);
    float4 bv = *(const float4*)(beta + d);
    float4 wg = {wv.x * gv.x, wv.y * gv.y, wv.z * gv.z, wv.w * gv.w};
    *(float4*)(ws + OFF_WG + d) = wg;
    float sg = wg.x + wg.y + wg.z + wg.w;
    float sb = wv.x * bv.x + wv.y * bv.y + wv.z * bv.z + wv.w * bv.w;
    __shared__ float lg[256], lb[256];
    lg[tid] = sg; lb[tid] = sb; __syncthreads();
    for (int off = 128; off > 0; off >>= 1) {
        if (tid < off) { lg[tid] += lg[tid + off]; lb[tid] += lb[tid + off]; }
        __syncthreads();
    }
    if (tid == 0) { ws[OFF_SCAL] = lg[0]; ws[OFF_SCAL + 1] = lb[0]; }
}

// K1 (fused): one block per (b,s). For each layer l: load V[l,b,s,:], block-reduce
// (sum, sumsq, wg-dot), score = rstd*(sw - mu*swg) + swb, p = exp(score) (no max
// shift -- softmax is shift-invariant and |score| <~ 5), accumulate U += p*V, z += p.
// Single chip-wide pass over V.
__global__ void arm_k1_fused(const float* __restrict__ hist, const float* __restrict__ cur,
                             const float* __restrict__ ws_ro, float* __restrict__ U,
                             float* __restrict__ ws) {
    int blk = blockIdx.x;          // b*S + s
    int b = blk / S, s = blk % S;
    int tid = threadIdx.x, lane = tid & 63, wid = tid >> 6;
    int d = tid * 4;

    float4 wg = *(const float4*)(ws_ro + OFF_WG + d);
    float swg = ws_ro[OFF_SCAL], swb = ws_ro[OFF_SCAL + 1];

    __shared__ float red[3][4];
    float4 acc = {0.f, 0.f, 0.f, 0.f};
    float zsum = 0.f;

    const float* rows[L1];
#pragma unroll
    for (int l = 0; l < 12; l++) rows[l] = hist + (((size_t)l * B + b) * S + s) * D;
    rows[12] = cur + ((size_t)b * S + s) * D;

#pragma unroll
    for (int l = 0; l < L1; l++) {
        float4 v = *(const float4*)(rows[l] + d);
        float s1 = v.x + v.y + v.z + v.w;
        float s2 = v.x * v.x + v.y * v.y + v.z * v.z + v.w * v.w;
        float sw = wg.x * v.x + wg.y * v.y + wg.z * v.z + wg.w * v.w;
#pragma unroll
        for (int off = 32; off > 0; off >>= 1) {
            s1 += __shfl_down(s1, off);
            s2 += __shfl_down(s2, off);
            sw += __shfl_down(sw, off);
        }
        if (lane == 0) { red[0][wid] = s1; red[1][wid] = s2; red[2][wid] = sw; }
        __syncthreads();
        s1 = red[0][0] + red[0][1] + red[0][2] + red[0][3];
        s2 = red[1][0] + red[1][1] + red[1][2] + red[1][3];
        sw = red[2][0] + red[2][1] + red[2][2] + red[2][3];
        float mu   = s1 * (1.0f / D);
        float var  = s2 * (1.0f / D) - mu * mu;
        float rstd = rsqrtf(var + EPS);
        float p = expf(rstd * (sw - mu * swg) + swb);
        acc.x += p * v.x; acc.y += p * v.y; acc.z += p * v.z; acc.w += p * v.w;
        zsum += p;
        __syncthreads();   // red[] reused next iteration
    }

    *(float4*)(U + ((size_t)b * S + s) * D + d) = acc;
    if (tid == 0) ws[OFF_Z + b * S + s] = zsum;
}

// K4: Zcum[b,s] = inclusive prefix sum of z over s. One block per b.
__global__ void arm_k4_zcum(float* __restrict__ ws) {
    int b = blockIdx.x, tid = threadIdx.x;  // 256 threads, 4 elems each
    const float* z = ws + OFF_Z + b * S;
    float* zc = ws + OFF_ZCUM + b * S;
    float v[4];
    float loc = 0.f;
#pragma unroll
    for (int j = 0; j < 4; j++) { v[j] = z[tid * 4 + j]; loc += v[j]; }
    __shared__ float lds[256];
    lds[tid] = loc; __syncthreads();
    for (int off = 1; off < 256; off <<= 1) {
        float t = (tid >= off) ? lds[tid - off] : 0.f;
        __syncthreads();
        lds[tid] += t;
        __syncthreads();
    }
    float run = lds[tid] - loc;  // exclusive offset
#pragma unroll
    for (int j = 0; j < 4; j++) { run += v[j]; zc[tid * 4 + j] = run; }
}

// K6a: per-chunk partial column sums of U
__global__ void arm_k6a_csum(const float* __restrict__ U, float* __restrict__ ws) {
    int blk = blockIdx.x;                 // b*NCH*(D/256) + ch*(D/256) + dblk
    int dblk = blk % (D / 256);
    int rem = blk / (D / 256);
    int ch = rem % NCH, b = rem / NCH;
    int d = dblk * 256 + threadIdx.x;
    const float* Ub = U + ((size_t)b * S + ch * CH) * D + d;
    float sum = 0.f;
#pragma unroll
    for (int j = 0; j < CH; j++) sum += Ub[(size_t)j * D];
    ws[OFF_CS + (b * NCH + ch) * D + d] = sum;
}

// K6b: exclusive scan of chunk sums over ch, in place
__global__ void arm_k6b_cscan(float* __restrict__ ws) {
    int blk = blockIdx.x;  // b*(D/256) + dblk
    int dblk = blk % (D / 256);
    int b = blk / (D / 256);
    int d = dblk * 256 + threadIdx.x;
    float* cs = ws + OFF_CS + b * NCH * D + d;
    float run = 0.f;
#pragma unroll
    for (int ch = 0; ch < NCH; ch++) {
        float v = cs[(size_t)ch * D];
        cs[(size_t)ch * D] = run;
        run += v;
    }
}

// K6c: local cumsum + divide by Zcum, in place over U (= d_out) -> h
__global__ void arm_k6c_final(float* __restrict__ U, const float* __restrict__ ws) {
    int blk = blockIdx.x;  // same mapping as k6a
    int dblk = blk % (D / 256);
    int rem = blk / (D / 256);
    int ch = rem % NCH, b = rem / NCH;
    int d = dblk * 256 + threadIdx.x;
    float run = ws[OFF_CS + (b * NCH + ch) * D + d];
    const float* zc = ws + OFF_ZCUM + b * S + ch * CH;
    float* Ub = U + ((size_t)b * S + ch * CH) * D + d;
#pragma unroll
    for (int j = 0; j < CH; j++) {
        run += Ub[(size_t)j * D];
        Ub[(size_t)j * D] = run / zc[j];
    }
}

extern "C" void kernel_launch(void* const* d_in, const int* in_sizes, int n_in,
                              void* d_out, int out_size, void* d_ws, size_t ws_size,
                              hipStream_t stream) {
    const float* hist  = (const float*)d_in[0];  // [12,B,S,D]
    const float* cur   = (const float*)d_in[1];  // [B,S,D]
    const float* w     = (const float*)d_in[2];  // [D]
    const float* gamma = (const float*)d_in[3];  // [D]
    const float* beta  = (const float*)d_in[4];  // [D]
    float* out = (float*)d_out;                  // [B,S,D]
    float* ws  = (float*)d_ws;

    arm_k0_prep<<<1, 256, 0, stream>>>(w, gamma, beta, ws);
    arm_k1_fused<<<B * S, 256, 0, stream>>>(hist, cur, ws, out, ws);
    arm_k4_zcum<<<B, 256, 0, stream>>>(ws);
    arm_k6a_csum<<<B * NCH * (D / 256), 256, 0, stream>>>(out, ws);
    arm_k6b_cscan<<<B * (D / 256), 256, 0, stream>>>(ws);
    arm_k6c_final<<<B * NCH * (D / 256), 256, 0, stream>>>(out, ws);
}

// Round 3
// 83.048 us; speedup vs baseline: 1.3311x; 1.0666x over previous
//
#include <hip/hip_runtime.h>
#include <math.h>

namespace {
constexpr int L1 = 13;   // 12 history layers + current
constexpr int LH = 12;
constexpr int B  = 4;
constexpr int S  = 1024;
constexpr int D  = 1024;
constexpr int NCH  = 32;        // s-chunks for the scan
constexpr int CH   = S / NCH;   // 32
constexpr int DBLK = D / 256;   // 4

// float offsets into workspace
constexpr int OFF_Z    = 0;              // [B][S]
constexpr int OFF_ZCUM = B * S;          // [B][S]
constexpr int OFF_CS   = 2 * B * S;      // [B][NCH][D] chunk partial sums
constexpr float EPS = 1e-5f;
constexpr int NV = 3 * L1 + 2;           // 41 block-reduce variables
}

// K1 (fully fused): one block (256 thr) per (b,s).
// Issue ALL 13 layer loads + w/gamma/beta up-front (deep MLP), per-wave shfl-reduce
// 41 vars (13x{sum,sumsq,wgdot} + swg + swb) into LDS partials, ONE barrier,
// finalize scores, p=exp(score) (softmax shift-invariant, |score|<~5),
// U = sum_l p*V, z = sum_l p.
__global__ __launch_bounds__(256) void arm_k1(const float* __restrict__ hist,
                                              const float* __restrict__ cur,
                                              const float* __restrict__ w,
                                              const float* __restrict__ gamma,
                                              const float* __restrict__ beta,
                                              float* __restrict__ U,
                                              float* __restrict__ ws) {
    int blk = blockIdx.x;
    int b = blk >> 10, s = blk & (S - 1);
    int tid = threadIdx.x, lane = tid & 63, wid = tid >> 6;
    int d = tid * 4;
    size_t off_bs = ((size_t)b * S + s) * D + d;

    float4 v[L1];
#pragma unroll
    for (int l = 0; l < LH; l++)
        v[l] = *(const float4*)(hist + (size_t)l * (B * S * D) + off_bs);
    v[12] = *(const float4*)(cur + off_bs);
    float4 wv = *(const float4*)(w + d);
    float4 gv = *(const float4*)(gamma + d);
    float4 bv = *(const float4*)(beta + d);

    float4 wg = {wv.x * gv.x, wv.y * gv.y, wv.z * gv.z, wv.w * gv.w};
    float swg_p = wg.x + wg.y + wg.z + wg.w;
    float swb_p = wv.x * bv.x + wv.y * bv.y + wv.z * bv.z + wv.w * bv.w;

    __shared__ float red[NV][4];

#pragma unroll
    for (int l = 0; l < L1; l++) {
        float s1 = v[l].x + v[l].y + v[l].z + v[l].w;
        float s2 = v[l].x * v[l].x + v[l].y * v[l].y + v[l].z * v[l].z + v[l].w * v[l].w;
        float sw = wg.x * v[l].x + wg.y * v[l].y + wg.z * v[l].z + wg.w * v[l].w;
#pragma unroll
        for (int off = 32; off > 0; off >>= 1) {
            s1 += __shfl_down(s1, off);
            s2 += __shfl_down(s2, off);
            sw += __shfl_down(sw, off);
        }
        if (lane == 0) { red[3 * l][wid] = s1; red[3 * l + 1][wid] = s2; red[3 * l + 2][wid] = sw; }
    }
    {
        float a = swg_p, c = swb_p;
#pragma unroll
        for (int off = 32; off > 0; off >>= 1) {
            a += __shfl_down(a, off);
            c += __shfl_down(c, off);
        }
        if (lane == 0) { red[NV - 2][wid] = a; red[NV - 1][wid] = c; }
    }
    __syncthreads();

    float swg = red[NV - 2][0] + red[NV - 2][1] + red[NV - 2][2] + red[NV - 2][3];
    float swb = red[NV - 1][0] + red[NV - 1][1] + red[NV - 1][2] + red[NV - 1][3];
    float4 acc = {0.f, 0.f, 0.f, 0.f};
    float zsum = 0.f;
#pragma unroll
    for (int l = 0; l < L1; l++) {
        float s1 = red[3 * l][0] + red[3 * l][1] + red[3 * l][2] + red[3 * l][3];
        float s2 = red[3 * l + 1][0] + red[3 * l + 1][1] + red[3 * l + 1][2] + red[3 * l + 1][3];
        float sw = red[3 * l + 2][0] + red[3 * l + 2][1] + red[3 * l + 2][2] + red[3 * l + 2][3];
        float mu   = s1 * (1.0f / D);
        float var  = s2 * (1.0f / D) - mu * mu;
        float rstd = rsqrtf(var + EPS);
        float p = __expf(rstd * (sw - mu * swg) + swb);
        acc.x += p * v[l].x; acc.y += p * v[l].y; acc.z += p * v[l].z; acc.w += p * v[l].w;
        zsum += p;
    }
    *(float4*)(U + off_bs) = acc;
    if (tid == 0) ws[OFF_Z + b * S + s] = zsum;
}

// K2: blocks [0, B*NCH*DBLK): per-chunk partial column sums of U.
//     blocks [B*NCH*DBLK, +B): inclusive prefix sum of z over s (one block per b).
__global__ void arm_k2(const float* __restrict__ U, float* __restrict__ ws) {
    int blk = blockIdx.x;
    int tid = threadIdx.x;
    if (blk >= B * NCH * DBLK) {
        int b = blk - B * NCH * DBLK;
        const float* z = ws + OFF_Z + b * S;
        float* zc = ws + OFF_ZCUM + b * S;
        float v[4];
        float loc = 0.f;
#pragma unroll
        for (int j = 0; j < 4; j++) { v[j] = z[tid * 4 + j]; loc += v[j]; }
        __shared__ float lds[256];
        lds[tid] = loc; __syncthreads();
        for (int off = 1; off < 256; off <<= 1) {
            float t = (tid >= off) ? lds[tid - off] : 0.f;
            __syncthreads();
            lds[tid] += t;
            __syncthreads();
        }
        float run = lds[tid] - loc;  // exclusive offset
#pragma unroll
        for (int j = 0; j < 4; j++) { run += v[j]; zc[tid * 4 + j] = run; }
        return;
    }
    int dblk = blk % DBLK;
    int rem = blk / DBLK;
    int ch = rem % NCH, b = rem / NCH;
    int d = dblk * 256 + tid;
    const float* Ub = U + ((size_t)b * S + ch * CH) * D + d;
    float sum = 0.f;
#pragma unroll
    for (int j = 0; j < CH; j++) sum += Ub[(size_t)j * D];
    ws[OFF_CS + (b * NCH + ch) * D + d] = sum;
}

// K3: per (b,ch,dblk): exclusive chunk-prefix from CS (redundant, L2-resident),
// then local cumsum over s within the chunk, divide by Zcum, write h in place (U = d_out).
__global__ void arm_k3(float* __restrict__ U, const float* __restrict__ ws) {
    int blk = blockIdx.x;
    int dblk = blk % DBLK;
    int rem = blk / DBLK;
    int ch = rem % NCH, b = rem / NCH;
    int d = dblk * 256 + threadIdx.x;

    const float* cs = ws + OFF_CS + b * NCH * D + d;
    float run = 0.f;
    for (int c2 = 0; c2 < ch; c2++) run += cs[(size_t)c2 * D];

    const float* zc = ws + OFF_ZCUM + b * S + ch * CH;
    float* Ub = U + ((size_t)b * S + ch * CH) * D + d;
#pragma unroll
    for (int j = 0; j < CH; j++) {
        run += Ub[(size_t)j * D];
        Ub[(size_t)j * D] = run / zc[j];
    }
}

extern "C" void kernel_launch(void* const* d_in, const int* in_sizes, int n_in,
                              void* d_out, int out_size, void* d_ws, size_t ws_size,
                              hipStream_t stream) {
    const float* hist  = (const float*)d_in[0];  // [12,B,S,D]
    const float* cur   = (const float*)d_in[1];  // [B,S,D]
    const float* w     = (const float*)d_in[2];  // [D]
    const float* gamma = (const float*)d_in[3];  // [D]
    const float* beta  = (const float*)d_in[4];  // [D]
    float* out = (float*)d_out;                  // [B,S,D]
    float* ws  = (float*)d_ws;

    arm_k1<<<B * S, 256, 0, stream>>>(hist, cur, w, gamma, beta, out, ws);
    arm_k2<<<B * NCH * DBLK + B, 256, 0, stream>>>(out, ws);
    arm_k3<<<B * NCH * DBLK, 256, 0, stream>>>(out, ws);
}